// Round 4
// baseline (5028.040 us; speedup 1.0000x reference)
//
#include <hip/hip_runtime.h>

#define SEQ 128
#define BSZ 64
#define EMB 32
#define HD  8
#define VOC 32000
#define P   8    // positions per block in output kernel

typedef float f32x4 __attribute__((ext_vector_type(4)));

// ---------------------------------------------------------------------------
// Kernel 0: xproj[s][b][h] = lookup[idx[s,b]] @ Wx + b1 + b2, both directions.
// Stored transposed per-thread-contiguous: xpf[(b*8+h)*SEQ + s].
// Backward copy is stored TIME-REVERSED so the scan always walks t=0..127.
// ---------------------------------------------------------------------------
__global__ __launch_bounds__(256) void xproj_kernel(
    const int*   __restrict__ idx,
    const float* __restrict__ lookup,
    const float* __restrict__ Wxf, const float* __restrict__ Wxb,
    const float* __restrict__ bf1, const float* __restrict__ bf2,
    const float* __restrict__ bb1, const float* __restrict__ bb2,
    float* __restrict__ xpf, float* __restrict__ xpb)
{
    const int i = blockIdx.x * 256 + threadIdx.x;   // flat (s*B + b)
    if (i >= SEQ * BSZ) return;
    const int s = i >> 6;          // / BSZ
    const int b = i & 63;          // % BSZ

    const float* xr = lookup + (size_t)idx[i] * EMB;
    float x[EMB];
#pragma unroll
    for (int e = 0; e < EMB; ++e) x[e] = xr[e];

#pragma unroll
    for (int h = 0; h < HD; ++h) {
        float af = bf1[h] + bf2[h];
        float ab = bb1[h] + bb2[h];
#pragma unroll
        for (int e = 0; e < EMB; ++e) {
            af = fmaf(x[e], Wxf[e * HD + h], af);
            ab = fmaf(x[e], Wxb[e * HD + h], ab);
        }
        xpf[(b * HD + h) * SEQ + s]             = af;
        xpb[(b * HD + h) * SEQ + (SEQ - 1 - s)] = ab;   // time-reversed
    }
}

// ---------------------------------------------------------------------------
// Kernel 1: the serial recurrence, pure-register.
// grid = 2 (dir), 512 threads = 64 batch x 8 hidden. Each thread preloads its
// 128 xproj values then runs a fully-unrolled 128-step scan:
// 8 shfl + 8 fma + fast tanh per step. Writes PREVIOUS state (lax.scan).
// ---------------------------------------------------------------------------
__global__ __launch_bounds__(512) void rnn_scan_kernel(
    const float* __restrict__ xpf, const float* __restrict__ xpb,
    const float* __restrict__ Whf, const float* __restrict__ Whb,
    const float* __restrict__ Hf0, const float* __restrict__ Hb0,
    float* __restrict__ Hcat)
{
    const int dir = blockIdx.x;
    const int tid = threadIdx.x;
    const int b   = tid >> 3;
    const int h   = tid & 7;

    const float* Wh = dir ? Whb : Whf;
    const float* xp = (dir ? xpb : xpf) + (size_t)tid * SEQ;

    float wh[HD];
#pragma unroll
    for (int j = 0; j < HD; ++j) wh[j] = Wh[j * HD + h];

    float xs[SEQ];
    const f32x4* xp4 = (const f32x4*)xp;
#pragma unroll
    for (int q = 0; q < SEQ / 4; ++q) {
        f32x4 v = xp4[q];
        xs[4 * q + 0] = v.x; xs[4 * q + 1] = v.y;
        xs[4 * q + 2] = v.z; xs[4 * q + 3] = v.w;
    }

    float hcur = dir ? Hb0[h] : Hf0[h];
    const int koff = dir ? HD : 0;

#pragma unroll
    for (int t = 0; t < SEQ; ++t) {
        const int s = dir ? (SEQ - 1 - t) : t;
        Hcat[(s * BSZ + b) * 16 + koff + h] = hcur;   // previous state

        float acc = xs[t];                            // static index
#pragma unroll
        for (int j = 0; j < HD; ++j)
            acc = fmaf(__shfl(hcur, j, 8), wh[j], acc);

        // tanh via exp; |acc| is bounded (~<6) so no overflow.
        float e = __expf(2.0f * acc);
        hcur = (e - 1.0f) / (e + 1.0f);
    }
}

// ---------------------------------------------------------------------------
// Kernel 2: logits = Hcat @ Wo + bo, log_softmax over V.
// grid = 1024 blocks x 256 threads; block owns P=8 positions x all V.
// Two passes over Wo (L2-resident; nontemporal output stores keep it there).
// No wave-minimum hint: natural VGPR ~130, no spills.
// ---------------------------------------------------------------------------
__global__ __launch_bounds__(256) void out_softmax_kernel(
    const float* __restrict__ Hcat,
    const float* __restrict__ Wo,
    const float* __restrict__ bo,
    float* __restrict__ out)
{
    __shared__ float hls[P][16];
    __shared__ float red[4][P];
    __shared__ float lsum[P];

    const int tid = threadIdx.x;
    const int pb  = blockIdx.x;

    if (tid < P * 16) hls[tid >> 4][tid & 15] = Hcat[pb * (P * 16) + tid];
    __syncthreads();

    float sacc[P];
#pragma unroll
    for (int p = 0; p < P; ++p) sacc[p] = 0.f;

    // ---- pass 1: sum of exp(logit); |logit| <= ~0.2 so max-subtract skipped
    for (int c = 0; c < 31; ++c) {
        const int v = c * 1024 + tid * 4;
        f32x4 bo4 = *(const f32x4*)(bo + v);
        f32x4 wo[16];
#pragma unroll
        for (int k = 0; k < 16; ++k) wo[k] = *(const f32x4*)(Wo + k * VOC + v);
#pragma unroll
        for (int p = 0; p < P; ++p) {
            f32x4 lg = bo4;
#pragma unroll
            for (int k = 0; k < 16; ++k)
                lg += wo[k] * hls[p][k];           // v_pk_fma_f32 via contract
            sacc[p] += __expf(lg.x) + __expf(lg.y) + __expf(lg.z) + __expf(lg.w);
        }
    }
    {   // remainder: v = 31744 + tid
        const int v = 31744 + tid;
        const float bos = bo[v];
        float woS[16];
#pragma unroll
        for (int k = 0; k < 16; ++k) woS[k] = Wo[k * VOC + v];
#pragma unroll
        for (int p = 0; p < P; ++p) {
            float lg = bos;
#pragma unroll
            for (int k = 0; k < 16; ++k) lg = fmaf(hls[p][k], woS[k], lg);
            sacc[p] += __expf(lg);
        }
    }

    // ---- block reduction ----
    const int lane = tid & 63;
    const int wv   = tid >> 6;
#pragma unroll
    for (int p = 0; p < P; ++p) {
        float s = sacc[p];
#pragma unroll
        for (int off = 32; off > 0; off >>= 1) s += __shfl_xor(s, off, 64);
        if (lane == 0) red[wv][p] = s;
    }
    __syncthreads();
    if (tid < P)
        lsum[tid] = logf(red[0][tid] + red[1][tid] + red[2][tid] + red[3][tid]);
    __syncthreads();

    float lsr[P];
#pragma unroll
    for (int p = 0; p < P; ++p) lsr[p] = lsum[p];

    // ---- pass 2: recompute logits, nontemporal write of log_softmax ----
    const size_t obase = (size_t)pb * P * VOC;
    for (int c = 0; c < 31; ++c) {
        const int v = c * 1024 + tid * 4;
        f32x4 bo4 = *(const f32x4*)(bo + v);
        f32x4 wo[16];
#pragma unroll
        for (int k = 0; k < 16; ++k) wo[k] = *(const f32x4*)(Wo + k * VOC + v);
#pragma unroll
        for (int p = 0; p < P; ++p) {
            f32x4 lg = bo4;
#pragma unroll
            for (int k = 0; k < 16; ++k)
                lg += wo[k] * hls[p][k];
            f32x4 o = lg - lsr[p];
            __builtin_nontemporal_store(o, (f32x4*)(out + obase + (size_t)p * VOC + v));
        }
    }
    {   // remainder
        const int v = 31744 + tid;
        const float bos = bo[v];
        float woS[16];
#pragma unroll
        for (int k = 0; k < 16; ++k) woS[k] = Wo[k * VOC + v];
#pragma unroll
        for (int p = 0; p < P; ++p) {
            float lg = bos;
#pragma unroll
            for (int k = 0; k < 16; ++k) lg = fmaf(hls[p][k], woS[k], lg);
            __builtin_nontemporal_store(lg - lsr[p], out + obase + (size_t)p * VOC + v);
        }
    }
}

extern "C" void kernel_launch(void* const* d_in, const int* in_sizes, int n_in,
                              void* d_out, int out_size, void* d_ws, size_t ws_size,
                              hipStream_t stream)
{
    const int*   idx    = (const int*)  d_in[0];
    const float* lookup = (const float*)d_in[1];
    const float* Wxf    = (const float*)d_in[2];
    const float* Whf    = (const float*)d_in[3];
    const float* Wxb    = (const float*)d_in[4];
    const float* Whb    = (const float*)d_in[5];
    const float* Wo     = (const float*)d_in[6];
    const float* Hf0    = (const float*)d_in[7];
    const float* Hb0    = (const float*)d_in[8];
    const float* bf1    = (const float*)d_in[9];
    const float* bf2    = (const float*)d_in[10];
    const float* bb1    = (const float*)d_in[11];
    const float* bb2    = (const float*)d_in[12];
    const float* bo     = (const float*)d_in[13];
    float* out = (float*)d_out;

    float* Hcat = (float*)d_ws;                       // 8192*16 f32 = 512 KB
    float* xpf  = Hcat + SEQ * BSZ * 16;              // 64*8*128 f32 = 256 KB
    float* xpb  = xpf + BSZ * HD * SEQ;               // 256 KB

    hipLaunchKernelGGL(xproj_kernel, dim3(SEQ * BSZ / 256), dim3(256), 0, stream,
                       idx, lookup, Wxf, Wxb, bf1, bf2, bb1, bb2, xpf, xpb);
    hipLaunchKernelGGL(rnn_scan_kernel, dim3(2), dim3(512), 0, stream,
                       xpf, xpb, Whf, Whb, Hf0, Hb0, Hcat);
    hipLaunchKernelGGL(out_softmax_kernel, dim3(SEQ * BSZ / P), dim3(256), 0, stream,
                       Hcat, Wo, bo, out);
}

// Round 5
// 946.880 us; speedup vs baseline: 5.3101x; 5.3101x over previous
//
#include <hip/hip_runtime.h>

#define SEQ 128
#define BSZ 64
#define EMB 32
#define HD  8
#define VOC 32000
#define P   16   // positions per block in output kernel

typedef float f32x4 __attribute__((ext_vector_type(4)));

// ---------------------------------------------------------------------------
// Kernel 0: xproj[s][b][h] = lookup[idx[s,b]] @ Wx + b1 + b2, both directions.
// Stored transposed per-thread-contiguous: xpf[(b*8+h)*SEQ + s].
// Backward copy is stored TIME-REVERSED so the scan always walks t=0..127.
// ---------------------------------------------------------------------------
__global__ __launch_bounds__(256) void xproj_kernel(
    const int*   __restrict__ idx,
    const float* __restrict__ lookup,
    const float* __restrict__ Wxf, const float* __restrict__ Wxb,
    const float* __restrict__ bf1, const float* __restrict__ bf2,
    const float* __restrict__ bb1, const float* __restrict__ bb2,
    float* __restrict__ xpf, float* __restrict__ xpb)
{
    const int i = blockIdx.x * 256 + threadIdx.x;   // flat (s*B + b)
    if (i >= SEQ * BSZ) return;
    const int s = i >> 6;          // / BSZ
    const int b = i & 63;          // % BSZ

    const float* xr = lookup + (size_t)idx[i] * EMB;
    float x[EMB];
#pragma unroll
    for (int e = 0; e < EMB; ++e) x[e] = xr[e];

#pragma unroll
    for (int h = 0; h < HD; ++h) {
        float af = bf1[h] + bf2[h];
        float ab = bb1[h] + bb2[h];
#pragma unroll
        for (int e = 0; e < EMB; ++e) {
            af = fmaf(x[e], Wxf[e * HD + h], af);
            ab = fmaf(x[e], Wxb[e * HD + h], ab);
        }
        xpf[(b * HD + h) * SEQ + s]             = af;
        xpb[(b * HD + h) * SEQ + (SEQ - 1 - s)] = ab;   // time-reversed
    }
}

// ---------------------------------------------------------------------------
// Kernel 1: the serial recurrence, pure-register.
// grid = 2 (dir), 512 threads = 64 batch x 8 hidden. Each thread preloads its
// 128 xproj values then runs a fully-unrolled 128-step scan:
// 8 shfl + 8 fma + fast tanh per step. Writes PREVIOUS state (lax.scan).
// ---------------------------------------------------------------------------
__global__ __launch_bounds__(512) void rnn_scan_kernel(
    const float* __restrict__ xpf, const float* __restrict__ xpb,
    const float* __restrict__ Whf, const float* __restrict__ Whb,
    const float* __restrict__ Hf0, const float* __restrict__ Hb0,
    float* __restrict__ Hcat)
{
    const int dir = blockIdx.x;
    const int tid = threadIdx.x;
    const int b   = tid >> 3;
    const int h   = tid & 7;

    const float* Wh = dir ? Whb : Whf;
    const float* xp = (dir ? xpb : xpf) + (size_t)tid * SEQ;

    float wh[HD];
#pragma unroll
    for (int j = 0; j < HD; ++j) wh[j] = Wh[j * HD + h];

    float xs[SEQ];
    const f32x4* xp4 = (const f32x4*)xp;
#pragma unroll
    for (int q = 0; q < SEQ / 4; ++q) {
        f32x4 v = xp4[q];
        xs[4 * q + 0] = v.x; xs[4 * q + 1] = v.y;
        xs[4 * q + 2] = v.z; xs[4 * q + 3] = v.w;
    }

    float hcur = dir ? Hb0[h] : Hf0[h];
    const int koff = dir ? HD : 0;

#pragma unroll
    for (int t = 0; t < SEQ; ++t) {
        const int s = dir ? (SEQ - 1 - t) : t;
        Hcat[(s * BSZ + b) * 16 + koff + h] = hcur;   // previous state

        float acc = xs[t];                            // static index
#pragma unroll
        for (int j = 0; j < HD; ++j)
            acc = fmaf(__shfl(hcur, j, 8), wh[j], acc);

        // tanh via exp; |acc| is bounded (~<6) so no overflow.
        float e = __expf(2.0f * acc);
        hcur = (e - 1.0f) / (e + 1.0f);
    }
}

// ---------------------------------------------------------------------------
// Kernel 2: logits = Hcat @ Wo + bo, log_softmax over V.
// grid = 512 blocks x 256 threads; block owns P=16 positions x all V.
// EXACT round-1 structure (scalar fmaf, proven spill-free at VGPR=256);
// the ONLY change: nontemporal output stores so the 1 GB output stream
// bypasses L2 and Wo (2 MB) stays L2-resident between the two passes.
// ---------------------------------------------------------------------------
__global__ __launch_bounds__(256) void out_softmax_kernel(
    const float* __restrict__ Hcat,
    const float* __restrict__ Wo,
    const float* __restrict__ bo,
    float* __restrict__ out)
{
    __shared__ float hls[P][16];
    __shared__ float red[4][P];
    __shared__ float lsum[P];

    const int tid = threadIdx.x;
    const int pb  = blockIdx.x;

    // Load the 16 h-values for each of the P positions (exactly 256 floats).
    hls[tid >> 4][tid & 15] = Hcat[pb * (P * 16) + tid];
    __syncthreads();

    float sacc[P];
#pragma unroll
    for (int p = 0; p < P; ++p) sacc[p] = 0.f;

    // ---- pass 1: sum of exp(logit); |logit| <= ~0.2 so max-subtract skipped
    for (int c = 0; c < 31; ++c) {
        const int v = c * 1024 + tid * 4;
        float4 bo4 = *(const float4*)(bo + v);
        float4 wo[16];
#pragma unroll
        for (int k = 0; k < 16; ++k) wo[k] = *(const float4*)(Wo + k * VOC + v);
#pragma unroll
        for (int p = 0; p < P; ++p) {
            float4 lg = bo4;
#pragma unroll
            for (int k = 0; k < 16; ++k) {
                const float hv = hls[p][k];
                lg.x = fmaf(hv, wo[k].x, lg.x);
                lg.y = fmaf(hv, wo[k].y, lg.y);
                lg.z = fmaf(hv, wo[k].z, lg.z);
                lg.w = fmaf(hv, wo[k].w, lg.w);
            }
            sacc[p] += __expf(lg.x) + __expf(lg.y) + __expf(lg.z) + __expf(lg.w);
        }
    }
    {   // remainder: v = 31744 + tid (256 values)
        const int v = 31744 + tid;
        const float bos = bo[v];
        float woS[16];
#pragma unroll
        for (int k = 0; k < 16; ++k) woS[k] = Wo[k * VOC + v];
#pragma unroll
        for (int p = 0; p < P; ++p) {
            float lg = bos;
#pragma unroll
            for (int k = 0; k < 16; ++k) lg = fmaf(hls[p][k], woS[k], lg);
            sacc[p] += __expf(lg);
        }
    }

    // ---- block reduction of sacc over 256 threads ----
    const int lane = tid & 63;
    const int wv   = tid >> 6;
#pragma unroll
    for (int p = 0; p < P; ++p) {
        float s = sacc[p];
#pragma unroll
        for (int off = 32; off > 0; off >>= 1) s += __shfl_xor(s, off, 64);
        if (lane == 0) red[wv][p] = s;
    }
    __syncthreads();
    if (tid < P) {
        lsum[tid] = logf(red[0][tid] + red[1][tid] + red[2][tid] + red[3][tid]);
    }
    __syncthreads();

    // ---- pass 2: recompute logits, nontemporal write of log_softmax ----
    const size_t obase = (size_t)pb * P * VOC;
    for (int c = 0; c < 31; ++c) {
        const int v = c * 1024 + tid * 4;
        float4 bo4 = *(const float4*)(bo + v);
        float4 wo[16];
#pragma unroll
        for (int k = 0; k < 16; ++k) wo[k] = *(const float4*)(Wo + k * VOC + v);
#pragma unroll
        for (int p = 0; p < P; ++p) {
            float4 lg = bo4;
#pragma unroll
            for (int k = 0; k < 16; ++k) {
                const float hv = hls[p][k];
                lg.x = fmaf(hv, wo[k].x, lg.x);
                lg.y = fmaf(hv, wo[k].y, lg.y);
                lg.z = fmaf(hv, wo[k].z, lg.z);
                lg.w = fmaf(hv, wo[k].w, lg.w);
            }
            const float ls = lsum[p];
            f32x4 o;
            o.x = lg.x - ls; o.y = lg.y - ls; o.z = lg.z - ls; o.w = lg.w - ls;
            __builtin_nontemporal_store(o, (f32x4*)(out + obase + (size_t)p * VOC + v));
        }
    }
    {   // remainder
        const int v = 31744 + tid;
        const float bos = bo[v];
        float woS[16];
#pragma unroll
        for (int k = 0; k < 16; ++k) woS[k] = Wo[k * VOC + v];
#pragma unroll
        for (int p = 0; p < P; ++p) {
            float lg = bos;
#pragma unroll
            for (int k = 0; k < 16; ++k) lg = fmaf(hls[p][k], woS[k], lg);
            __builtin_nontemporal_store(lg - lsum[p], out + obase + (size_t)p * VOC + v);
        }
    }
}

extern "C" void kernel_launch(void* const* d_in, const int* in_sizes, int n_in,
                              void* d_out, int out_size, void* d_ws, size_t ws_size,
                              hipStream_t stream)
{
    const int*   idx    = (const int*)  d_in[0];
    const float* lookup = (const float*)d_in[1];
    const float* Wxf    = (const float*)d_in[2];
    const float* Whf    = (const float*)d_in[3];
    const float* Wxb    = (const float*)d_in[4];
    const float* Whb    = (const float*)d_in[5];
    const float* Wo     = (const float*)d_in[6];
    const float* Hf0    = (const float*)d_in[7];
    const float* Hb0    = (const float*)d_in[8];
    const float* bf1    = (const float*)d_in[9];
    const float* bf2    = (const float*)d_in[10];
    const float* bb1    = (const float*)d_in[11];
    const float* bb2    = (const float*)d_in[12];
    const float* bo     = (const float*)d_in[13];
    float* out = (float*)d_out;

    float* Hcat = (float*)d_ws;                       // 8192*16 f32 = 512 KB
    float* xpf  = Hcat + SEQ * BSZ * 16;              // 64*8*128 f32 = 256 KB
    float* xpb  = xpf + BSZ * HD * SEQ;               // 256 KB

    hipLaunchKernelGGL(xproj_kernel, dim3(SEQ * BSZ / 256), dim3(256), 0, stream,
                       idx, lookup, Wxf, Wxb, bf1, bf2, bb1, bb2, xpf, xpb);
    hipLaunchKernelGGL(rnn_scan_kernel, dim3(2), dim3(512), 0, stream,
                       xpf, xpb, Whf, Whb, Hf0, Hb0, Hcat);
    hipLaunchKernelGGL(out_softmax_kernel, dim3(SEQ * BSZ / P), dim3(256), 0, stream,
                       Hcat, Wo, bo, out);
}

// Round 6
// 291.953 us; speedup vs baseline: 17.2221x; 3.2433x over previous
//
#include <hip/hip_runtime.h>

#define SEQ 128
#define BSZ 64
#define EMB 32
#define HD  8
#define VOC 32000
#define NPOS (SEQ * BSZ)          // 8192 positions
#define NRB  (NPOS / 32)          // 256 row-blocks of 32 positions
#define NVS  40                   // v-splits; 1000 v-tiles = 40 * 25
#define TPW  25                   // v-tiles per wave

typedef float f32x4  __attribute__((ext_vector_type(4)));
typedef short bf16x8 __attribute__((ext_vector_type(8)));
typedef float f32x16 __attribute__((ext_vector_type(16)));

// round-to-nearest-even f32 -> bf16 bits
__device__ __forceinline__ unsigned short f2bf(float f) {
    union { float f; unsigned int u; } x; x.f = f;
    unsigned int r = x.u + 0x7fffu + ((x.u >> 16) & 1u);
    return (unsigned short)(r >> 16);
}

// ---------------------------------------------------------------------------
// Kernel 0: xproj = lookup[idx] @ Wx + b1 + b2 (both dirs), thread-contiguous,
// backward copy stored time-reversed.
// ---------------------------------------------------------------------------
__global__ __launch_bounds__(256) void xproj_kernel(
    const int*   __restrict__ idx,
    const float* __restrict__ lookup,
    const float* __restrict__ Wxf, const float* __restrict__ Wxb,
    const float* __restrict__ bf1, const float* __restrict__ bf2,
    const float* __restrict__ bb1, const float* __restrict__ bb2,
    float* __restrict__ xpf, float* __restrict__ xpb)
{
    const int i = blockIdx.x * 256 + threadIdx.x;
    if (i >= NPOS) return;
    const int s = i >> 6;
    const int b = i & 63;

    const float* xr = lookup + (size_t)idx[i] * EMB;
    float x[EMB];
#pragma unroll
    for (int e = 0; e < EMB; ++e) x[e] = xr[e];

#pragma unroll
    for (int h = 0; h < HD; ++h) {
        float af = bf1[h] + bf2[h];
        float ab = bb1[h] + bb2[h];
#pragma unroll
        for (int e = 0; e < EMB; ++e) {
            af = fmaf(x[e], Wxf[e * HD + h], af);
            ab = fmaf(x[e], Wxb[e * HD + h], ab);
        }
        xpf[(b * HD + h) * SEQ + s]             = af;
        xpb[(b * HD + h) * SEQ + (SEQ - 1 - s)] = ab;
    }
}

// ---------------------------------------------------------------------------
// Kernel 1: serial recurrence, pure-register; emits bf16 Hcat (hc2[pos][16]).
// ---------------------------------------------------------------------------
__global__ __launch_bounds__(512) void rnn_scan_kernel(
    const float* __restrict__ xpf, const float* __restrict__ xpb,
    const float* __restrict__ Whf, const float* __restrict__ Whb,
    const float* __restrict__ Hf0, const float* __restrict__ Hb0,
    unsigned short* __restrict__ hc2)
{
    const int dir = blockIdx.x;
    const int tid = threadIdx.x;
    const int b   = tid >> 3;
    const int h   = tid & 7;

    const float* Wh = dir ? Whb : Whf;
    const float* xp = (dir ? xpb : xpf) + (size_t)tid * SEQ;

    float wh[HD];
#pragma unroll
    for (int j = 0; j < HD; ++j) wh[j] = Wh[j * HD + h];

    float xs[SEQ];
    const f32x4* xp4 = (const f32x4*)xp;
#pragma unroll
    for (int q = 0; q < SEQ / 4; ++q) {
        f32x4 v = xp4[q];
        xs[4 * q + 0] = v.x; xs[4 * q + 1] = v.y;
        xs[4 * q + 2] = v.z; xs[4 * q + 3] = v.w;
    }

    float hcur = dir ? Hb0[h] : Hf0[h];
    const int koff = dir ? HD : 0;

#pragma unroll
    for (int t = 0; t < SEQ; ++t) {
        const int s = dir ? (SEQ - 1 - t) : t;
        hc2[(s * BSZ + b) * 16 + koff + h] = f2bf(hcur);   // previous state

        float acc = xs[t];
#pragma unroll
        for (int j = 0; j < HD; ++j)
            acc = fmaf(__shfl(hcur, j, 8), wh[j], acc);

        float e = __expf(2.0f * acc);
        hcur = (e - 1.0f) / (e + 1.0f);
    }
}

// ---------------------------------------------------------------------------
// Kernel 2: Wo (f32 [16][32000]) -> wt (bf16 [32000][16], transposed).
// ---------------------------------------------------------------------------
__global__ __launch_bounds__(256) void wo_prep_kernel(
    const float* __restrict__ Wo, unsigned short* __restrict__ wt)
{
    const int v = blockIdx.x * 256 + threadIdx.x;
    if (v >= VOC) return;
#pragma unroll
    for (int k = 0; k < 16; ++k)
        wt[v * 16 + k] = f2bf(Wo[k * VOC + v]);
}

// ---------------------------------------------------------------------------
// Kernel 3: partial exp-sums. Wave = (row-block rb, v-split vs); 25 v-tiles.
// MFMA 32x32x16 bf16: D col=lane&31, row=(reg&3)+8*(reg>>2)+4*(lane>>5).
// A frag: lane l holds hc2[rb*32 + (l&31)][8*(l>>5) + 0..7].
// B frag: lane l holds wt[v0 + (l&31)][8*(l>>5) + 0..7].
// ---------------------------------------------------------------------------
__global__ __launch_bounds__(256) void lse_partial_kernel(
    const unsigned short* __restrict__ hc2,
    const unsigned short* __restrict__ wt,
    const float* __restrict__ bo,
    float* __restrict__ partial)
{
    const int gw   = blockIdx.x * 4 + (threadIdx.x >> 6);   // global wave id
    const int rb   = gw / NVS;
    const int vs   = gw - rb * NVS;
    const int lane = threadIdx.x & 63;
    const int half = lane >> 5;
    const int lc   = lane & 31;

    const bf16x8 afrag = *(const bf16x8*)(hc2 + (size_t)(rb * 32 + lc) * 16 + half * 8);

    f32x16 zv;
#pragma unroll
    for (int i = 0; i < 16; ++i) zv[i] = 0.0f;

    float sacc[16];
#pragma unroll
    for (int g = 0; g < 16; ++g) sacc[g] = 0.0f;

    for (int t = 0; t < TPW; ++t) {
        const int v0 = (vs * TPW + t) * 32;
        const bf16x8 bfrag = *(const bf16x8*)(wt + (size_t)(v0 + lc) * 16 + half * 8);
        f32x16 d = __builtin_amdgcn_mfma_f32_32x32x16_bf16(afrag, bfrag, zv, 0, 0, 0);
        const float bov = bo[v0 + lc];
#pragma unroll
        for (int g = 0; g < 16; ++g)
            sacc[g] += __expf(d[g] + bov);
    }

    // reduce each sacc[g] across the 32 lanes of this half
#pragma unroll
    for (int g = 0; g < 16; ++g) {
        float s = sacc[g];
        s += __shfl_xor(s, 1, 32);
        s += __shfl_xor(s, 2, 32);
        s += __shfl_xor(s, 4, 32);
        s += __shfl_xor(s, 8, 32);
        s += __shfl_xor(s, 16, 32);
        sacc[g] = s;
    }

    if (lc == 0) {
#pragma unroll
        for (int g = 0; g < 16; ++g) {
            const int row = (g & 3) + 8 * (g >> 2) + 4 * half;
            partial[(size_t)(rb * 32 + row) * NVS + vs] = sacc[g];
        }
    }
}

// ---------------------------------------------------------------------------
// Kernel 4: lse[row] = log( sum_vs partial[row][vs] )
// ---------------------------------------------------------------------------
__global__ __launch_bounds__(256) void lse_reduce_kernel(
    const float* __restrict__ partial, float* __restrict__ lse)
{
    const int row = blockIdx.x * 256 + threadIdx.x;
    if (row >= NPOS) return;
    const f32x4* p4 = (const f32x4*)(partial + (size_t)row * NVS);
    float s = 0.0f;
#pragma unroll
    for (int q = 0; q < NVS / 4; ++q) {
        f32x4 v = p4[q];
        s += v.x + v.y + v.z + v.w;
    }
    lse[row] = logf(s);
}

// ---------------------------------------------------------------------------
// Kernel 5: out = logits - lse, recomputed via MFMA, nontemporal stores.
// Same wave decomposition as kernel 3. Each store instr writes 2x128B lines.
// ---------------------------------------------------------------------------
__global__ __launch_bounds__(256) void out_mfma_kernel(
    const unsigned short* __restrict__ hc2,
    const unsigned short* __restrict__ wt,
    const float* __restrict__ bo,
    const float* __restrict__ lse,
    float* __restrict__ out)
{
    const int gw   = blockIdx.x * 4 + (threadIdx.x >> 6);
    const int rb   = gw / NVS;
    const int vs   = gw - rb * NVS;
    const int lane = threadIdx.x & 63;
    const int half = lane >> 5;
    const int lc   = lane & 31;

    const bf16x8 afrag = *(const bf16x8*)(hc2 + (size_t)(rb * 32 + lc) * 16 + half * 8);

    f32x16 zv;
#pragma unroll
    for (int i = 0; i < 16; ++i) zv[i] = 0.0f;

    // per-lane lse for its 16 (reg) rows
    float lse16[16];
#pragma unroll
    for (int g = 0; g < 16; ++g) {
        const int row = (g & 3) + 8 * (g >> 2) + 4 * half;
        lse16[g] = lse[rb * 32 + row];
    }

    for (int t = 0; t < TPW; ++t) {
        const int v0 = (vs * TPW + t) * 32;
        const bf16x8 bfrag = *(const bf16x8*)(wt + (size_t)(v0 + lc) * 16 + half * 8);
        f32x16 d = __builtin_amdgcn_mfma_f32_32x32x16_bf16(afrag, bfrag, zv, 0, 0, 0);
        const float bov = bo[v0 + lc];
#pragma unroll
        for (int g = 0; g < 16; ++g) {
            const int row = (g & 3) + 8 * (g >> 2) + 4 * half;
            const float val = d[g] + bov - lse16[g];
            __builtin_nontemporal_store(
                val, out + (size_t)(rb * 32 + row) * VOC + v0 + lc);
        }
    }
}

extern "C" void kernel_launch(void* const* d_in, const int* in_sizes, int n_in,
                              void* d_out, int out_size, void* d_ws, size_t ws_size,
                              hipStream_t stream)
{
    const int*   idx    = (const int*)  d_in[0];
    const float* lookup = (const float*)d_in[1];
    const float* Wxf    = (const float*)d_in[2];
    const float* Whf    = (const float*)d_in[3];
    const float* Wxb    = (const float*)d_in[4];
    const float* Whb    = (const float*)d_in[5];
    const float* Wo     = (const float*)d_in[6];
    const float* Hf0    = (const float*)d_in[7];
    const float* Hb0    = (const float*)d_in[8];
    const float* bf1    = (const float*)d_in[9];
    const float* bf2    = (const float*)d_in[10];
    const float* bb1    = (const float*)d_in[11];
    const float* bb2    = (const float*)d_in[12];
    const float* bo     = (const float*)d_in[13];
    float* out = (float*)d_out;

    // workspace layout (all 16B-aligned)
    char* ws = (char*)d_ws;
    float*          xpf     = (float*)ws;                    ws += BSZ * HD * SEQ * 4;   // 256 KB
    float*          xpb     = (float*)ws;                    ws += BSZ * HD * SEQ * 4;   // 256 KB
    unsigned short* hc2     = (unsigned short*)ws;           ws += NPOS * 16 * 2;        // 256 KB
    unsigned short* wt      = (unsigned short*)ws;           ws += VOC * 16 * 2;         // 1 MB
    float*          partial = (float*)ws;                    ws += (size_t)NPOS * NVS * 4; // 1.31 MB
    float*          lse     = (float*)ws;                    ws += NPOS * 4;             // 32 KB

    hipLaunchKernelGGL(xproj_kernel, dim3(NPOS / 256), dim3(256), 0, stream,
                       idx, lookup, Wxf, Wxb, bf1, bf2, bb1, bb2, xpf, xpb);
    hipLaunchKernelGGL(wo_prep_kernel, dim3((VOC + 255) / 256), dim3(256), 0, stream,
                       Wo, wt);
    hipLaunchKernelGGL(rnn_scan_kernel, dim3(2), dim3(512), 0, stream,
                       xpf, xpb, Whf, Whb, Hf0, Hb0, hc2);
    hipLaunchKernelGGL(lse_partial_kernel, dim3(NRB * NVS / 4), dim3(256), 0, stream,
                       hc2, wt, bo, partial);
    hipLaunchKernelGGL(lse_reduce_kernel, dim3(NPOS / 256), dim3(256), 0, stream,
                       partial, lse);
    hipLaunchKernelGGL(out_mfma_kernel, dim3(NRB * NVS / 4), dim3(256), 0, stream,
                       hc2, wt, bo, lse, out);
}